// Round 4
// baseline (28.924 us; speedup 1.0000x reference)
//
#include <hip/hip_runtime.h>
#include <hip/hip_bf16.h>
#include <math.h>

// Problem constants (mirror the reference module-level config)
#define IMG_H     256
#define IMG_W     256
#define N_BLOCKS  512
#define TILES     1024   // (256/8)*(256/8)
#define BATCH     32
#define GRID_W    32     // tiles per image row
#define PAD       72     // LDS row pad (floats); 72*4=288B is 16B-aligned

typedef float f32x4 __attribute__((ext_vector_type(4)));

// One 64-lane wave per 4 consecutive (b,l) rows: 16 independent 16B loads in
// flight (4x the MLP of the previous version), batched butterfly argmax for
// all 4 rows, then 16 tiles per block staged in LDS and written as float4.
__global__ __launch_bounds__(256) void ImageReconstruction_55825984913931_kernel(
    const int*   __restrict__ frame_idxs,   // [BATCH]
    const float* __restrict__ sequence,     // [N_SEQ, TILES, N_BLOCKS]
    const float* __restrict__ blocks,       // [N_BLOCKS, 8, 8]
    const float* __restrict__ gumbel,       // [BATCH, TILES, N_BLOCKS]
    float*       __restrict__ out)          // [BATCH, 1, 256, 256]
{
    __shared__ float tilebuf[16][PAD];

    const int wave      = threadIdx.x >> 6;       // 4 waves per block
    const int lane      = threadIdx.x & 63;
    const int blockBase = blockIdx.x * 16;        // 16 consecutive tiles/block
    const int b         = blockBase >> 10;        // same image for all 16 (16|1024)
    const int fi        = frame_idxs[b];
    const int l0        = (blockBase & (TILES - 1)) + wave * 4;  // wave's first tile

    const float* __restrict__ seq_base = sequence + ((size_t)fi * TILES + l0) * N_BLOCKS;
    const float* __restrict__ gum_base = gumbel   + ((size_t)b  * TILES + l0) * N_BLOCKS;

    // Issue all 16 loads (8KB seq + 8KB gum per wave, contiguous) before use.
    f32x4 s[4][2], g[4][2];
    #pragma unroll
    for (int r = 0; r < 4; ++r) {
        #pragma unroll
        for (int c = 0; c < 2; ++c) {
            const int off = r * N_BLOCKS + c * 256 + lane * 4;
            s[r][c] = *reinterpret_cast<const f32x4*>(seq_base + off);
            g[r][c] = *reinterpret_cast<const f32x4*>(gum_base + off);
        }
    }

    // Per-lane argmax (increasing index + strict '>' keeps earliest max).
    float best[4]; int bidx[4];
    #pragma unroll
    for (int r = 0; r < 4; ++r) {
        best[r] = -INFINITY; bidx[r] = 0x7fffffff;
        #pragma unroll
        for (int c = 0; c < 2; ++c) {
            const int base = c * 256 + lane * 4;
            #pragma unroll
            for (int j = 0; j < 4; ++j) {
                const float v = s[r][c][j] + g[r][c][j];
                if (v > best[r]) { best[r] = v; bidx[r] = base + j; }
            }
        }
    }

    // Batched butterfly reduce, 4 rows together; tie-break: lowest index.
    #pragma unroll
    for (int off = 32; off >= 1; off >>= 1) {
        #pragma unroll
        for (int r = 0; r < 4; ++r) {
            const float ov = __shfl_xor(best[r], off, 64);
            const int   oi = __shfl_xor(bidx[r], off, 64);
            if (ov > best[r] || (ov == best[r] && oi < bidx[r])) {
                best[r] = ov; bidx[r] = oi;
            }
        }
    }

    // Gather winning blocks (table is 128KB, L2-resident) into LDS.
    #pragma unroll
    for (int r = 0; r < 4; ++r)
        tilebuf[wave * 4 + r][lane] = blocks[bidx[r] * 64 + lane];
    __syncthreads();

    // Cooperative write: block region = 8 image rows x 128 cols (16 tiles in
    // one tile-row). Thread t writes one float4; each wave covers 2 rows of
    // 512B contiguous.
    const int t      = threadIdx.x;
    const int r_img  = t >> 5;            // 0..7
    const int c4     = (t & 31) * 4;      // 0..124, step 4
    const int tile   = c4 >> 3;           // 0..15
    const int within = r_img * 8 + (c4 & 7);
    const f32x4 v = *reinterpret_cast<const f32x4*>(&tilebuf[tile][within]);

    const int ti  = (blockBase & (TILES - 1)) >> 5;  // tile row
    const int tj0 = blockBase & (GRID_W - 1);        // first tile col (mult of 16)
    float* dst = out + (size_t)b * (IMG_H * IMG_W)
                     + (ti * 8 + r_img) * IMG_W + tj0 * 8 + c4;
    *reinterpret_cast<f32x4*>(dst) = v;
}

extern "C" void kernel_launch(void* const* d_in, const int* in_sizes, int n_in,
                              void* d_out, int out_size, void* d_ws, size_t ws_size,
                              hipStream_t stream) {
    const int*   frame_idxs = (const int*)  d_in[0];
    const float* sequence   = (const float*)d_in[1];
    const float* blocks     = (const float*)d_in[2];
    const float* gumbel     = (const float*)d_in[3];
    float*       out        = (float*)      d_out;

    const int grid = (BATCH * TILES) / 16;   // 2048 blocks, 16 tiles each
    ImageReconstruction_55825984913931_kernel<<<grid, 256, 0, stream>>>(
        frame_idxs, sequence, blocks, gumbel, out);
}